// Round 2
// baseline (1208.248 us; speedup 1.0000x reference)
//
#include <hip/hip_runtime.h>

// FilterStage3x3: out = 3x3_filter(softmax(Wc @ f + bc), x)
// B=2, F=128, C=3, H=720, W=1280, 9 taps, fp32.
// Memory-bound: mandatory HBM traffic ~988 MB (f dominates) -> ~155 us floor.

#define BB 2
#define FF 128
#define CC 3
#define HH 720
#define WW 1280
#define PPT 4              // pixels per thread (float4 along W)
#define BLOCK 256
#define PIPE 8             // f channels in flight per thread (32 VGPRs of data)

__global__ __launch_bounds__(BLOCK) void filter3x3_kernel(
    const float* __restrict__ f,
    const float* __restrict__ x,
    const float* __restrict__ Wc,
    const float* __restrict__ bc,
    float* __restrict__ out)
{
    // Weights transposed + padded: sW[ch][tap], 12 floats/row (48 B, 16B-aligned)
    // -> per channel: 2x ds_read_b128 + 1x ds_read_b32 (vs 9x ds_read_b32).
    __shared__ float sW[FF][12];

    const int tid = threadIdx.x;
    for (int i = tid; i < 9 * FF; i += BLOCK) {
        const int o  = i / FF;
        const int ch = i % FF;
        sW[ch][o] = Wc[i];
    }
    __syncthreads();

    // thread -> (b, h, w)
    const int t   = blockIdx.x * BLOCK + tid;   // grid exact, no guard
    const int WG  = WW / PPT;                   // 320
    const int w4  = t % WG;
    const int tmp = t / WG;
    const int h   = tmp % HH;
    const int b   = tmp / HH;
    const int w   = w4 * PPT;

    // ---- 1x1 conv: 9 logits x 4 pixels, software-pipelined over channels ----
    float acc[9][PPT];
    #pragma unroll
    for (int o = 0; o < 9; ++o) {
        const float bv = bc[o];                 // uniform scalar load, once
        #pragma unroll
        for (int p = 0; p < PPT; ++p) acc[o][p] = bv;
    }

    const size_t planeF = (size_t)HH * WW;      // 921600
    const float* fp = f + ((size_t)b * FF * HH + h) * WW + w;

    float4 buf[PIPE];
    #pragma unroll
    for (int j = 0; j < PIPE; ++j)
        buf[j] = *(const float4*)(fp + (size_t)j * planeF);

    #define FMA_CH(ch_, fv_)                                                 \
    {                                                                        \
        const float4 wa = *(const float4*)&sW[(ch_)][0];                     \
        const float4 wb = *(const float4*)&sW[(ch_)][4];                     \
        const float  w8 = sW[(ch_)][8];                                      \
        const float wv[9] = {wa.x, wa.y, wa.z, wa.w, wb.x, wb.y, wb.z, wb.w, w8}; \
        _Pragma("unroll")                                                    \
        for (int o = 0; o < 9; ++o) {                                        \
            acc[o][0] = fmaf((fv_).x, wv[o], acc[o][0]);                     \
            acc[o][1] = fmaf((fv_).y, wv[o], acc[o][1]);                     \
            acc[o][2] = fmaf((fv_).z, wv[o], acc[o][2]);                     \
            acc[o][3] = fmaf((fv_).w, wv[o], acc[o][3]);                     \
        }                                                                    \
    }

    #pragma unroll 1
    for (int c0 = 0; c0 < FF - PIPE; c0 += PIPE) {
        #pragma unroll
        for (int j = 0; j < PIPE; ++j) {
            const float4 fv = buf[j];
            buf[j] = *(const float4*)(fp + (size_t)(c0 + j + PIPE) * planeF); // prefetch
            FMA_CH(c0 + j, fv);
        }
    }
    #pragma unroll
    for (int j = 0; j < PIPE; ++j) {            // epilogue chunk, no prefetch
        const float4 fv = buf[j];
        FMA_CH(FF - PIPE + j, fv);
    }

    // ---- softmax over the 9 taps, in place ----
    #pragma unroll
    for (int p = 0; p < PPT; ++p) {
        float m = acc[0][p];
        #pragma unroll
        for (int o = 1; o < 9; ++o) m = fmaxf(m, acc[o][p]);
        float s = 0.f;
        #pragma unroll
        for (int o = 0; o < 9; ++o) {
            const float e = __expf(acc[o][p] - m);
            acc[o][p] = e;
            s += e;
        }
        const float inv = 1.f / s;
        #pragma unroll
        for (int o = 0; o < 9; ++o) acc[o][p] *= inv;
    }

    // ---- 3x3 neighborhood combine of x ----
    const bool interior = (h >= 1) & (h < HH - 1) & (w >= 4) & (w <= WW - 8);
    if (interior) {
        #pragma unroll
        for (int c = 0; c < CC; ++c) {
            float o0 = 0.f, o1 = 0.f, o2 = 0.f, o3 = 0.f;
            #pragma unroll
            for (int dy = 0; dy < 3; ++dy) {
                const float* xr = x + ((size_t)(b * CC + c) * HH + (h + dy - 1)) * WW + w;
                float xv[PPT + 2];
                #pragma unroll
                for (int j = 0; j < PPT + 2; ++j) xv[j] = xr[j - 1];
                #pragma unroll
                for (int dx = 0; dx < 3; ++dx) {
                    const int o = dy * 3 + dx;
                    o0 = fmaf(acc[o][0], xv[dx + 0], o0);
                    o1 = fmaf(acc[o][1], xv[dx + 1], o1);
                    o2 = fmaf(acc[o][2], xv[dx + 2], o2);
                    o3 = fmaf(acc[o][3], xv[dx + 3], o3);
                }
            }
            *(float4*)(out + ((size_t)(b * CC + c) * HH + h) * WW + w) =
                make_float4(o0, o1, o2, o3);
        }
    } else {
        #pragma unroll
        for (int c = 0; c < CC; ++c) {
            float o0 = 0.f, o1 = 0.f, o2 = 0.f, o3 = 0.f;
            #pragma unroll
            for (int dy = 0; dy < 3; ++dy) {
                const int row = h + dy - 1;
                const bool vr = (row >= 0) && (row < HH);
                const float* xr = x + ((size_t)(b * CC + c) * HH + row) * WW;
                float xv[PPT + 2];
                #pragma unroll
                for (int j = 0; j < PPT + 2; ++j) {
                    const int col = w - 1 + j;
                    xv[j] = (vr && col >= 0 && col < WW) ? xr[col] : 0.f;
                }
                #pragma unroll
                for (int dx = 0; dx < 3; ++dx) {
                    const int o = dy * 3 + dx;
                    o0 = fmaf(acc[o][0], xv[dx + 0], o0);
                    o1 = fmaf(acc[o][1], xv[dx + 1], o1);
                    o2 = fmaf(acc[o][2], xv[dx + 2], o2);
                    o3 = fmaf(acc[o][3], xv[dx + 3], o3);
                }
            }
            *(float4*)(out + ((size_t)(b * CC + c) * HH + h) * WW + w) =
                make_float4(o0, o1, o2, o3);
        }
    }
    #undef FMA_CH
}

extern "C" void kernel_launch(void* const* d_in, const int* in_sizes, int n_in,
                              void* d_out, int out_size, void* d_ws, size_t ws_size,
                              hipStream_t stream) {
    const float* f  = (const float*)d_in[0];
    const float* x  = (const float*)d_in[1];
    const float* Wc = (const float*)d_in[2];
    const float* bc = (const float*)d_in[3];
    float* out = (float*)d_out;

    const int total_threads = BB * HH * (WW / PPT);   // 460800
    const int grid = total_threads / BLOCK;           // 1800, exact
    filter3x3_kernel<<<grid, BLOCK, 0, stream>>>(f, x, Wc, bc, out);
}